// Round 11
// baseline (39.926 us; speedup 1.0000x reference)
//
#include <hip/hip_runtime.h>

// Depthwise 7x7 'same' conv, fp32 in/out. B=16, C=256, H=W=64.
// R1 mapping (wave = half-plane, lane = 4w x 8h tile) + dot2 inner
// product, but the 14 row-steps are a ROLLED loop (#pragma unroll 1)
// with a rotating 7-slot accumulator line buffer:
//   slot k at iter j holds output row oi = j-6+k; input row r=hb-3+j
//   contributes kernel row kr = 6-k to slot k (STATIC mapping);
//   slot 0 completes each iter (j>=6) -> store row j-6, shift, zero slot 6.
// Rationale: every previous variant fully unrolled ~20-25 KB of code;
// all plateaued at VALUBusy 26-41% with every data pipe idle ->
// instruction-fetch-bound hypothesis. This body is ~1.3 KB (I$-resident).

typedef _Float16 v2h __attribute__((ext_vector_type(2)));

static __device__ __forceinline__ v2h pack2(float a, float b) {
    return __builtin_bit_cast(v2h, __builtin_amdgcn_cvt_pkrtz(a, b));
}

__global__ __launch_bounds__(256, 2)
void dwconv7x7_rolled(const float* __restrict__ x,
                      const float* __restrict__ weight,
                      const float* __restrict__ bias,
                      float* __restrict__ out) {
    const int tid  = threadIdx.x;
    const int lane = tid & 63;
    const int wid  = tid >> 6;
    const int gw   = blockIdx.x * 4 + wid;   // 0..8191
    const int plane = gw >> 1;               // b*256 + c
    const int half  = gw & 1;
    const int c = __builtin_amdgcn_readfirstlane(plane & 255);

    // ---- per-channel weights (uniform): half2 pairs in SGPRs ----
    const float* wp = weight + c * 49;
    float wk[49];
#pragma unroll
    for (int k = 0; k < 49; ++k) wk[k] = wp[k];
    const float bv = bias[c];

    v2h  W[7][3];     // taps (0,1),(2,3),(4,5) per kernel row
    float w6[7];      // tap 6 scalar
#pragma unroll
    for (int kr = 0; kr < 7; ++kr) {
#pragma unroll
        for (int t = 0; t < 3; ++t) {
            v2h p = pack2(wk[kr * 7 + 2 * t], wk[kr * 7 + 2 * t + 1]);
            int b = __builtin_amdgcn_readfirstlane(__builtin_bit_cast(int, p));
            W[kr][t] = __builtin_bit_cast(v2h, b);
        }
        w6[kr] = wk[kr * 7 + 6];
    }

    const int tx = lane & 15;        // 16 tiles across width
    const int sy = lane >> 4;        // 4 strips per half-plane
    const int wb = tx * 4;           // output col base
    const int hb = half * 32 + sy * 8;

    const float* xp = x + (size_t)plane * 4096;
    const int offm = (tx > 0)  ? (wb - 4) : wb;   // clamped aligned left
    const int offp = (tx < 15) ? (wb + 4) : wb;   // clamped aligned right

    // rotating accumulator line buffer: slot k <-> output row j-6+k
    float accR[7][4];
#pragma unroll
    for (int k = 0; k < 7; ++k)
#pragma unroll
        for (int jj = 0; jj < 4; ++jj) accR[k][jj] = 0.f;

    float* op = out + (size_t)plane * 4096 + (size_t)hb * 64 + wb;

#pragma unroll 1
    for (int j = 0; j < 14; ++j) {
        const int r  = hb - 3 + j;
        const int rc = min(max(r, 0), 63);
        const float* rowp = xp + rc * 64;
        const bool mrow = (r >= 0) && (r < 64);
        const bool mm = mrow && (tx > 0);
        const bool mp = mrow && (tx < 15);

        float4 qm = *reinterpret_cast<const float4*>(rowp + offm);
        float4 q0 = *reinterpret_cast<const float4*>(rowp + wb);
        float4 qp = *reinterpret_cast<const float4*>(rowp + offp);

        // f[i] = x[r][wb-3+i], i = 0..9 (masked to zero outside)
        float f[10];
        f[0] = mm   ? qm.y : 0.f;
        f[1] = mm   ? qm.z : 0.f;
        f[2] = mm   ? qm.w : 0.f;
        f[3] = mrow ? q0.x : 0.f;
        f[4] = mrow ? q0.y : 0.f;
        f[5] = mrow ? q0.z : 0.f;
        f[6] = mrow ? q0.w : 0.f;
        f[7] = mp   ? qp.x : 0.f;
        f[8] = mp   ? qp.y : 0.f;
        f[9] = mp   ? qp.z : 0.f;

        // sliding half2 pairs: pk[t] = (f[t], f[t+1])
        v2h pk[8];
#pragma unroll
        for (int t = 0; t < 8; ++t) pk[t] = pack2(f[t], f[t + 1]);

        // slot k receives kernel row kr = 6-k (static)
#pragma unroll
        for (int k = 0; k < 7; ++k) {
            const int kr = 6 - k;
#pragma unroll
            for (int jj = 0; jj < 4; ++jj) {
                float a = fmaf(f[jj + 6], w6[kr], accR[k][jj]);
                a = __builtin_amdgcn_fdot2(pk[jj + 4], W[kr][2], a, false);
                a = __builtin_amdgcn_fdot2(pk[jj + 2], W[kr][1], a, false);
                a = __builtin_amdgcn_fdot2(pk[jj],     W[kr][0], a, false);
                accR[k][jj] = a;
            }
        }

        // slot 0 (output row j-6) is complete -> store with bias
        if (j >= 6) {
            float4 v;
            v.x = accR[0][0] + bv;
            v.y = accR[0][1] + bv;
            v.z = accR[0][2] + bv;
            v.w = accR[0][3] + bv;
            *reinterpret_cast<float4*>(op + (j - 6) * 64) = v;
        }

        // shift line buffer, zero incoming slot
#pragma unroll
        for (int k = 0; k < 6; ++k)
#pragma unroll
            for (int jj = 0; jj < 4; ++jj) accR[k][jj] = accR[k + 1][jj];
#pragma unroll
        for (int jj = 0; jj < 4; ++jj) accR[6][jj] = 0.f;
    }
}

extern "C" void kernel_launch(void* const* d_in, const int* in_sizes, int n_in,
                              void* d_out, int out_size, void* d_ws, size_t ws_size,
                              hipStream_t stream) {
    const float* x      = (const float*)d_in[0];
    const float* weight = (const float*)d_in[1];
    const float* bias   = (const float*)d_in[2];
    float* out          = (float*)d_out;
    (void)in_sizes; (void)n_in; (void)out_size; (void)d_ws; (void)ws_size;

    // 8192 waves = 2048 blocks x 256 threads (4 waves/block)
    dim3 grid(2048);
    dim3 block(256);
    dwconv7x7_rolled<<<grid, block, 0, stream>>>(x, weight, bias, out);
}